// Round 1
// 243.573 us; speedup vs baseline: 1.0224x; 1.0224x over previous
//
#include <hip/hip_runtime.h>
#include <hip/hip_bf16.h>

typedef __hip_bfloat16 bf16;
typedef unsigned short u16;
typedef __attribute__((ext_vector_type(8))) short bf16x8;     // MFMA A/B frag: 8 bf16 = 4 VGPRs
typedef __attribute__((ext_vector_type(4))) float f32x4;      // MFMA C/D frag
typedef __attribute__((ext_vector_type(8))) unsigned short u16x8;

#define KD 1024
#define HD 1024
#define BSZ 8192
#define BM 128
#define BN 64
#define BK 32

// ws layout (bytes): wt [0, 12582912) | xb [12582912, +16777216) | hb [29360128, +16777216)
#define WS_XB 12582912
#define WS_HB 29360128
#define WS_NEED 46137344ULL

__device__ __forceinline__ u16 f2b(float f) {
    return __builtin_bit_cast(u16, __float2bfloat16(f));
}

// ---- async global->LDS, 16B per lane, wave-uniform LDS base + lane*16 ----
__device__ __forceinline__ void gload16(const void* g, u16* smem, int lds_byte_off) {
    __builtin_amdgcn_global_load_lds(
        (const __attribute__((address_space(1))) void*)g,
        (__attribute__((address_space(3))) void*)((char*)smem + lds_byte_off),
        16, 0, 0);
}

// ---------------------------------------------------------------------------
// Kernel A: one-shot f32 -> bf16 conversion of x and hid.
// ---------------------------------------------------------------------------
__global__ __launch_bounds__(256) void convert_xh(
    const float* __restrict__ x, const float* __restrict__ h,
    u16* __restrict__ xb, u16* __restrict__ hb)
{
    size_t off = ((size_t)blockIdx.x * 256 + threadIdx.x) * 8;   // <<<4096,256>>> covers 8M elems
    float4 a0 = *(const float4*)(x + off);
    float4 a1 = *(const float4*)(x + off + 4);
    float4 b0 = *(const float4*)(h + off);
    float4 b1 = *(const float4*)(h + off + 4);
    u16x8 vx, vh;
    vx[0]=f2b(a0.x); vx[1]=f2b(a0.y); vx[2]=f2b(a0.z); vx[3]=f2b(a0.w);
    vx[4]=f2b(a1.x); vx[5]=f2b(a1.y); vx[6]=f2b(a1.z); vx[7]=f2b(a1.w);
    vh[0]=f2b(b0.x); vh[1]=f2b(b0.y); vh[2]=f2b(b0.z); vh[3]=f2b(b0.w);
    vh[4]=f2b(b1.x); vh[5]=f2b(b1.y); vh[6]=f2b(b1.z); vh[7]=f2b(b1.w);
    *(u16x8*)(xb + off) = vx;
    *(u16x8*)(hb + off) = vh;
}

// ---------------------------------------------------------------------------
// Kernel B: transpose+cast weights [g][k][n] f32 -> wt[g][n][k] bf16.
// ---------------------------------------------------------------------------
__global__ __launch_bounds__(256) void transpose_w(
    const float* __restrict__ wx, const float* __restrict__ wh, u16* __restrict__ wt)
{
    __shared__ u16 tile[64][65];   // +1 pad breaks bank collisions
    const int g = blockIdx.z;
    const float* src = (g < 3) ? (wx + (size_t)g * KD * HD) : (wh + (size_t)(g - 3) * KD * HD);
    u16* dst = wt + (size_t)g * KD * HD;
    const int r0 = blockIdx.y * 64;   // k rows in src
    const int c0 = blockIdx.x * 64;   // n cols in src
    const int t = threadIdx.x;

    #pragma unroll
    for (int r = 0; r < 2; r++) {
        int idx = r * 256 + t;
        int row = idx >> 3, cc = idx & 7;
        const float* p = src + (size_t)(r0 + row) * HD + c0 + cc * 8;
        #pragma unroll
        for (int e = 0; e < 8; e++) tile[row][cc * 8 + e] = f2b(p[e]);
    }
    __syncthreads();
    #pragma unroll
    for (int r = 0; r < 2; r++) {
        int idx = r * 256 + t;
        int nrow = idx >> 3, kc = idx & 7;
        u16x8 v;
        #pragma unroll
        for (int e = 0; e < 8; e++) v[e] = tile[kc * 8 + e][nrow];
        *(u16x8*)(dst + (size_t)(c0 + nrow) * KD + r0 + kc * 8) = v;
    }
}

// ---------------------------------------------------------------------------
// Epilogue shared by both GEMM variants. C/D layout: col=lane&15, row=quad*4+r.
// ---------------------------------------------------------------------------
__device__ __forceinline__ void gru_epilogue(
    f32x4 (&acc)[4][4][2], const float* __restrict__ bxf, const float* __restrict__ bhf,
    const float* __restrict__ hidf, float* __restrict__ outf,
    int m0, int n0, int wm, int wn, int quad, int c16)
{
    float bR[2], bZ[2], bXN[2], bHN[2];
    #pragma unroll
    for (int j = 0; j < 2; j++) {
        int col = n0 + wn * 32 + j * 16 + c16;
        bR[j]  = bxf[col]          + bhf[col];
        bZ[j]  = bxf[HD + col]     + bhf[HD + col];
        bXN[j] = bxf[2 * HD + col];
        bHN[j] = bhf[2 * HD + col];
    }
    #pragma unroll
    for (int i = 0; i < 4; i++)
        #pragma unroll
        for (int j = 0; j < 2; j++) {
            int col = n0 + wn * 32 + j * 16 + c16;
            #pragma unroll
            for (int r = 0; r < 4; r++) {
                int row = m0 + wm * 64 + i * 16 + quad * 4 + r;
                size_t idx = (size_t)row * HD + col;
                float vr = acc[0][i][j][r] + bR[j];
                vr = 1.f / (1.f + __expf(-vr));
                float vz = acc[1][i][j][r] + bZ[j];
                vz = 1.f / (1.f + __expf(-vz));
                float vn = (acc[2][i][j][r] + bXN[j]) + vr * (acc[3][i][j][r] + bHN[j]);
                float e2 = __expf(2.f * vn);
                vn = 1.f - 2.f / (e2 + 1.f);
                float o = (1.f - vz) * vn + vz * hidf[idx];
                outf[idx] = o;
            }
        }
}

// ---------------------------------------------------------------------------
// Stage one K-step (BK=32) tile set into LDS buffer at byte base `bufb`.
// Layout within buffer (bytes): x0 [0,4K) x1 [4K,8K) h0 [8K,12K) h1 [12K,16K)
// w[g] at 16K + g*4K. Total 40960 B per buffer.
// ---------------------------------------------------------------------------
__device__ __forceinline__ void kstep_stage(
    const u16* gx0, const u16* gx1, const u16* gh0, const u16* gh1,
    const u16* gw0, u16* smem, int bufb, int ldsl)
{
    gload16(gx0, smem, bufb + ldsl);
    gload16(gx1, smem, bufb + 4096 + ldsl);
    gload16(gh0, smem, bufb + 8192 + ldsl);
    gload16(gh1, smem, bufb + 12288 + ldsl);
    #pragma unroll
    for (int g = 0; g < 6; g++)
        gload16(gw0 + (size_t)g * KD * HD, smem, bufb + 16384 + g * 4096 + ldsl);
}

// ---------------------------------------------------------------------------
// Compute one K-step from LDS buffer starting at u16 offset (sm pointer).
// ---------------------------------------------------------------------------
__device__ __forceinline__ void kstep_compute(
    const u16* sm, f32x4 (&acc)[4][4][2], int wm, int wn, int quad, int c16)
{
    bf16x8 ax[4], ah[4];
    #pragma unroll
    for (int i = 0; i < 4; i++) {
        int ml = wm * 64 + i * 16 + c16;
        ax[i] = *(const bf16x8*)&sm[ml * BK + quad * 8];
        ah[i] = *(const bf16x8*)&sm[4096 + ml * BK + quad * 8];
    }
    #pragma unroll
    for (int p = 0; p < 3; p++) {
        bf16x8 bwx[2], bwh[2];
        #pragma unroll
        for (int j = 0; j < 2; j++) {
            int nl = wn * 32 + j * 16 + c16;
            bwx[j] = *(const bf16x8*)&sm[8192 + p * 2048       + nl * BK + quad * 8];
            bwh[j] = *(const bf16x8*)&sm[8192 + (p + 3) * 2048 + nl * BK + quad * 8];
        }
        #pragma unroll
        for (int i = 0; i < 4; i++)
            #pragma unroll
            for (int j = 0; j < 2; j++) {
                if (p < 2) {
                    acc[p][i][j] = __builtin_amdgcn_mfma_f32_16x16x32_bf16(ax[i], bwx[j], acc[p][i][j], 0, 0, 0);
                    acc[p][i][j] = __builtin_amdgcn_mfma_f32_16x16x32_bf16(ah[i], bwh[j], acc[p][i][j], 0, 0, 0);
                } else {
                    acc[2][i][j] = __builtin_amdgcn_mfma_f32_16x16x32_bf16(ax[i], bwx[j], acc[2][i][j], 0, 0, 0);
                    acc[3][i][j] = __builtin_amdgcn_mfma_f32_16x16x32_bf16(ah[i], bwh[j], acc[3][i][j], 0, 0, 0);
                }
            }
    }
}

// ---------------------------------------------------------------------------
// Kernel C (fast): double-buffered 2-phase pipeline (T3 minimal form).
// Per K-step: issue next-tile global_load_lds FIRST, then ds_read+MFMA the
// current buffer, then ONE __syncthreads() (its vmcnt(0) drain now lands
// after ~480 cy of MFMA instead of before it). LDS = 2 x 40960 B = 80 KiB;
// occupancy unchanged (2 blocks/CU, VGPR-limited by the 128-reg accumulator).
// ---------------------------------------------------------------------------
__global__ __launch_bounds__(256, 2) void gru_fused_fast(
    const u16* __restrict__ xb, const u16* __restrict__ hb,
    const u16* __restrict__ wt,
    const float* __restrict__ bxf, const float* __restrict__ bhf,
    const float* __restrict__ hidf, float* __restrict__ outf)
{
    __shared__ u16 smem[40960];   // 80 KiB: two 40960-byte buffers
    const int t    = threadIdx.x;
    const int lane = t & 63;
    const int w    = t >> 6;
    const int wm   = w >> 1, wn = w & 1;
    const int quad = lane >> 4;
    const int c16  = lane & 15;
    // XCD swizzle: linear % 8 presumed XCD; give each XCD 2 n-blocks so its
    // 1.57 MB weight slice stays L2-resident.
    const int lin  = blockIdx.x;
    const int nblk = (lin & 7) * 2 + ((lin >> 3) & 1);
    const int mblk = lin >> 4;
    const int m0   = mblk * BM;
    const int n0   = nblk * BN;

    const int row4 = t >> 2;
    const int e8   = (t & 3) * 8;
    const u16* gx0 = xb + (size_t)(m0 + row4) * KD + e8;
    const u16* gx1 = gx0 + (size_t)64 * KD;
    const u16* gh0 = hb + (size_t)(m0 + row4) * KD + e8;
    const u16* gh1 = gh0 + (size_t)64 * KD;
    const u16* gw0 = wt + (size_t)(n0 + row4) * KD + e8;
    const int ldsl = w * 1024;   // wave-uniform LDS byte base (lane adds *16)

    f32x4 acc[4][4][2];
    #pragma unroll
    for (int a = 0; a < 4; a++)
        #pragma unroll
        for (int i = 0; i < 4; i++)
            #pragma unroll
            for (int j = 0; j < 2; j++)
                acc[a][i][j] = (f32x4){0.f, 0.f, 0.f, 0.f};

    const int NT = KD / BK;   // 32

    // prologue: stage k-step 0 into buffer 0, drain, barrier
    kstep_stage(gx0, gx1, gh0, gh1, gw0, smem, 0, ldsl);
    gx0 += BK; gx1 += BK; gh0 += BK; gh1 += BK; gw0 += BK;
    __syncthreads();

    // steady state: stage t+1 into buf[(t+1)&1] while computing t from buf[t&1].
    // Hazards: WAR on stage target covered by previous iteration's barrier
    // (all waves' ds_reads of that buffer drained via lgkmcnt before it);
    // RAW on compute buffer covered by the same barrier's vmcnt(0) drain.
    for (int tt = 0; tt < NT - 1; ++tt) {
        kstep_stage(gx0, gx1, gh0, gh1, gw0, smem, ((tt + 1) & 1) * 40960, ldsl);
        gx0 += BK; gx1 += BK; gh0 += BK; gh1 += BK; gw0 += BK;
        kstep_compute(smem + (tt & 1) * 20480, acc, wm, wn, quad, c16);
        __syncthreads();
    }
    // epilogue K-step: buffer (NT-1)&1 == 1, staged and drained by last iter
    kstep_compute(smem + 20480, acc, wm, wn, quad, c16);

    gru_epilogue(acc, bxf, bhf, hidf, outf, m0, n0, wm, wn, quad, c16);
}

// ---------------------------------------------------------------------------
// Kernel C' (fallback if ws too small for xb/hb): unchanged single-buffer path.
// ---------------------------------------------------------------------------
__global__ __launch_bounds__(256, 2) void gru_fused_slow(
    const float* __restrict__ xf, const float* __restrict__ hf,
    const u16* __restrict__ wt,
    const float* __restrict__ bxf, const float* __restrict__ bhf,
    float* __restrict__ outf)
{
    __shared__ u16 smem[20480];
    const int t    = threadIdx.x;
    const int lane = t & 63;
    const int w    = t >> 6;
    const int wm   = w >> 1, wn = w & 1;
    const int quad = lane >> 4;
    const int c16  = lane & 15;
    const int lin  = blockIdx.x;
    const int nblk = (lin & 7) * 2 + ((lin >> 3) & 1);
    const int mblk = lin >> 4;
    const int m0   = mblk * BM;
    const int n0   = nblk * BN;
    const int row4 = t >> 2;
    const int e8   = (t & 3) * 8;
    const u16* gw0 = wt + (size_t)(n0 + row4) * KD + e8;
    const int ldsl = w * 1024;

    f32x4 acc[4][4][2];
    #pragma unroll
    for (int a = 0; a < 4; a++)
        #pragma unroll
        for (int i = 0; i < 4; i++)
            #pragma unroll
            for (int j = 0; j < 2; j++)
                acc[a][i][j] = (f32x4){0.f, 0.f, 0.f, 0.f};

    for (int k0 = 0; k0 < KD; k0 += BK) {
        #pragma unroll
        for (int g = 0; g < 6; g++)
            gload16(gw0 + (size_t)g * KD * HD, smem, 16384 + g * 4096 + ldsl);
        gw0 += BK;
        #pragma unroll
        for (int s = 0; s < 2; s++) {
            size_t gidx = (size_t)(m0 + s * 64 + row4) * KD + k0 + e8;
            const float* px = xf + gidx;
            const float* ph = hf + gidx;
            u16x8 vx, vh;
            #pragma unroll
            for (int e = 0; e < 8; e++) { vx[e] = f2b(px[e]); vh[e] = f2b(ph[e]); }
            *(u16x8*)&smem[s * 2048 + t * 8] = vx;
            *(u16x8*)&smem[4096 + s * 2048 + t * 8] = vh;
        }
        __syncthreads();
        kstep_compute(smem, acc, wm, wn, quad, c16);
        __syncthreads();
    }

    gru_epilogue(acc, bxf, bhf, hf, outf, m0, n0, wm, wn, quad, c16);
}

extern "C" void kernel_launch(void* const* d_in, const int* in_sizes, int n_in,
                              void* d_out, int out_size, void* d_ws, size_t ws_size,
                              hipStream_t stream) {
    const float* x   = (const float*)d_in[0];
    const float* hid = (const float*)d_in[1];
    const float* wx  = (const float*)d_in[2];
    const float* wh  = (const float*)d_in[3];
    const float* bx  = (const float*)d_in[4];
    const float* bh  = (const float*)d_in[5];
    float* out = (float*)d_out;

    char* ws = (char*)d_ws;
    u16* wt = (u16*)ws;
    u16* xb = (u16*)(ws + WS_XB);
    u16* hb = (u16*)(ws + WS_HB);

    dim3 tgrid(HD / 64, KD / 64, 6);
    transpose_w<<<tgrid, 256, 0, stream>>>(wx, wh, wt);

    if (ws_size >= WS_NEED) {
        convert_xh<<<4096, 256, 0, stream>>>(x, hid, xb, hb);
        gru_fused_fast<<<1024, 256, 0, stream>>>(xb, hb, wt, bx, bh, hid, out);
    } else {
        gru_fused_slow<<<1024, 256, 0, stream>>>(x, hid, wt, bx, bh, out);
    }
}